// Round 13
// baseline (164.271 us; speedup 1.0000x reference)
//
#include <hip/hip_runtime.h>

typedef unsigned short u16;
typedef __bf16 bf16x8 __attribute__((ext_vector_type(8)));
typedef float f32x4 __attribute__((ext_vector_type(4)));

#define N_ 16384
#define SCALE 0.35355339059327379f   // 64^-0.25

__device__ __forceinline__ u16 f2bf(float f){
  union { float f; unsigned int i; } v; v.f = f;
  unsigned int b = v.i;
  return (u16)((b + 0x7FFFu + ((b >> 16) & 1u)) >> 16);
}
// packed RNE f32x2 -> bf16x2 (bit-identical to f2bf pair, 1 instr)
__device__ __forceinline__ unsigned int cvtpk(float a, float b){
  unsigned int r;
  asm("v_cvt_pk_bf16_f32 %0, %1, %2" : "=v"(r) : "v"(a), "v"(b));
  return r;
}

// ---------------------------------------------------------------------------
// pconvx = prep + convx fused (R7-proven, unchanged).
// ---------------------------------------------------------------------------
__global__ __launch_bounds__(256) void pconvx(const float* __restrict__ x,
    u16* __restrict__ xt, const float* __restrict__ Wq,
    const float* __restrict__ bq, const float* __restrict__ Wk,
    const float* __restrict__ bk, const float* __restrict__ Wv,
    const float* __restrict__ bv, u16* __restrict__ wkvf, u16* __restrict__ wqf,
    float* __restrict__ bkv, float* __restrict__ bqs){
  const int tid = threadIdx.x;
  const int bid = blockIdx.x;
  if (bid < 512){
    const int b = bid >> 7;
    const int kq = tid >> 6;                           // wave = k-quarter
    const int t0 = (bid & 127) * 128 + 2 * (tid & 63); // 2 tokens / thread
    const float* xp = x + (size_t)(b * 128 + kq * 32) * N_ + t0;
    u16* dst = xt + (size_t)(b * N_ + t0) * 128;
#pragma unroll
    for (int gi = 0; gi < 4; gi++){
      float2 v[8];
#pragma unroll
      for (int j = 0; j < 8; j++)
        v[j] = *(const float2*)(xp + (size_t)(gi * 8 + j) * N_);
      const int g = kq * 4 + gi;
      {
        uint4 o;
        o.x = cvtpk(v[0].x, v[1].x); o.y = cvtpk(v[2].x, v[3].x);
        o.z = cvtpk(v[4].x, v[5].x); o.w = cvtpk(v[6].x, v[7].x);
        *(uint4*)(dst + ((g ^ (t0 & 15)) * 8)) = o;
      }
      {
        uint4 o;
        o.x = cvtpk(v[0].y, v[1].y); o.y = cvtpk(v[2].y, v[3].y);
        o.z = cvtpk(v[4].y, v[5].y); o.w = cvtpk(v[6].y, v[7].y);
        const int t = t0 + 1;
        *(uint4*)(dst + 128 + ((g ^ (t & 15)) * 8)) = o;
      }
    }
    return;
  }
  // ---- prep path ----
  const int T = (bid - 512) * 256 + tid;   // 0..24575
  if (T < 1024){
    int jj = T & 127, h = T >> 7;
    bkv[T] = (jj < 64) ? SCALE * bk[h * 64 + jj] : bv[h * 64 + jj - 64];
  } else if (T < 1536){
    bqs[T - 1024] = SCALE * bq[T - 1024];
  }
  const float* src; float sc; u16* dst;
  if (T < 16384){
    int l = T & 63, f = T >> 6;
    int ks = f & 3, jt = (f >> 2) & 7, h = f >> 5;
    int jj = 16 * jt + (l & 15);
    int k0 = ks * 32 + (l >> 4) * 8;
    if (jj < 64){ src = Wk + (size_t)(h * 64 + jj) * 128 + k0; sc = SCALE; }
    else        { src = Wv + (size_t)(h * 64 + jj - 64) * 128 + k0; sc = 1.f; }
    dst = wkvf + (size_t)f * 512 + l * 8;
  } else {
    int T2 = T - 16384;
    int l = T2 & 63, f = T2 >> 6;
    int ks = f & 3, dt = (f >> 2) & 3, h = f >> 4;
    int d = 16 * dt + (l & 15);
    int k0 = ks * 32 + (l >> 4) * 8;
    src = Wq + (size_t)(h * 64 + d) * 128 + k0; sc = SCALE;
    dst = wqf + (size_t)f * 512 + l * 8;
  }
  float4 a = *(const float4*)src, c = *(const float4*)(src + 4);
  ushort4 o0, o1;
  o0.x = f2bf(sc * a.x); o0.y = f2bf(sc * a.y); o0.z = f2bf(sc * a.z); o0.w = f2bf(sc * a.w);
  o1.x = f2bf(sc * c.x); o1.y = f2bf(sc * c.y); o1.z = f2bf(sc * c.z); o1.w = f2bf(sc * c.w);
  *(ushort4*)dst = o0; *(ushort4*)(dst + 4) = o1;
}

// ---------------------------------------------------------------------------
// kvctx v10 (R12-measured) + T5 setprio around MFMA clusters.
// ---------------------------------------------------------------------------
__global__ __launch_bounds__(256, 2) void kvctx(const u16* __restrict__ xt,
    const u16* __restrict__ wkvf, const float* __restrict__ bkv,
    float* __restrict__ pctx, float* __restrict__ prs){
  __shared__ u16 smem[32768];   // sx [0,32768)B ; sekv [32768,65536)B ; fb overlay
  const int tid = threadIdx.x;
  const int cp = blockIdx.x, h = blockIdx.y, b = blockIdx.z;  // cp = chunk pair
  const int w = tid >> 6, l = tid & 63, r15 = l & 15, q = l >> 4;
  const int th = w & 1, jh = w >> 1;

  // balanced j-tile map: ni 0,1 -> K-tiles 2jh+ni (rows<64, exp'd);
  //                      ni 2,3 -> V-tiles 4+2jh+(ni-2) (rows>=64)
  int jt_[4];
#pragma unroll
  for (int ni = 0; ni < 4; ni++) jt_[ni] = (ni < 2) ? (2 * jh + ni) : (2 + 2 * jh + ni);

  bf16x8 wf[4][4];
#pragma unroll
  for (int ni = 0; ni < 4; ni++)
#pragma unroll
    for (int ks = 0; ks < 4; ks++)
      wf[ni][ks] = *(const bf16x8*)(wkvf +
          (size_t)((h * 8 + jt_[ni]) * 4 + ks) * 512 + l * 8);
  float barr[4];
#pragma unroll
  for (int ni = 0; ni < 4; ni++)
    barr[ni] = bkv[h * 128 + jt_[ni] * 16 + r15];

  const size_t tok0 = (size_t)b * N_ + cp * 1024;
  const char* gbase = (const char*)(xt + tok0 * 128);  // 1024 rows x 256 B
  u16* sekv = smem + 16384;

#define STAGE(sub_)                                                            \
  {                                                                            \
    const char* gs = gbase + (size_t)(sub_)*32768 + w * 8192 + l * 16;         \
    char* ls = (char*)smem + w * 8192;                                         \
    _Pragma("unroll")                                                          \
    for (int p = 0; p < 8; p++)                                                \
      __builtin_amdgcn_global_load_lds(                                        \
          (const __attribute__((address_space(1))) void*)(gs + p * 1024),      \
          (__attribute__((address_space(3))) void*)(ls + p * 1024), 16, 0, 0); \
  }

  STAGE(0);
  __syncthreads();   // sub0 x-tile ready

  f32x4 acc2[4][4] = {};
  float rs[2] = {0.f, 0.f};

  for (int sub = 0; sub < 8; sub++){
    f32x4 acc1[4][4] = {};
#pragma unroll
    for (int ks = 0; ks < 4; ks++){
      bf16x8 xa[4];
#pragma unroll
      for (int mi = 0; mi < 4; mi++){
        int t = th * 64 + 16 * mi + r15;
        xa[mi] = *(const bf16x8*)&smem[t * 128 + (((ks * 4 + q) ^ r15) * 8)];
      }
      __builtin_amdgcn_s_setprio(1);
#pragma unroll
      for (int mi = 0; mi < 4; mi++)
#pragma unroll
        for (int ni = 0; ni < 4; ni++)
          acc1[mi][ni] = __builtin_amdgcn_mfma_f32_16x16x32_bf16(
              xa[mi], wf[ni][ks], acc1[mi][ni], 0, 0, 0);
      __builtin_amdgcn_s_setprio(0);
    }
    // B0 (lgkm-only): all waves done READING sx -> safe to overwrite
    asm volatile("s_waitcnt lgkmcnt(0)" ::: "memory");
    __builtin_amdgcn_s_barrier();
    if (sub < 7) STAGE(sub + 1);   // flies under softmax + MFMA2
#pragma unroll
    for (int ni = 0; ni < 4; ni++){
      const float bb = barr[ni];
      const int j = jt_[ni] * 16 + r15;
      float ps = 0.f;
#pragma unroll
      for (int mi = 0; mi < 4; mi++){
        float vals[4];
#pragma unroll
        for (int r = 0; r < 4; r++) vals[r] = acc1[mi][ni][r] + bb;
        if (ni < 2){
#pragma unroll
          for (int r = 0; r < 4; r++){ vals[r] = __expf(vals[r]); ps += vals[r]; }
        }
        uint2 pk;
        pk.x = cvtpk(vals[0], vals[1]);
        pk.y = cvtpk(vals[2], vals[3]);
        int g8 = 16 * th + 4 * mi + q;
        int g8s = g8 ^ (2 * r15);
        *(uint2*)&sekv[j * 128 + g8s * 4] = pk;
      }
      if (ni < 2){
        ps += __shfl_xor(ps, 16); ps += __shfl_xor(ps, 32);
        rs[ni] += ps;
      }
    }
    // B1 (lgkm-only): sekv writes visible; staging vmcnt NOT drained
    asm volatile("s_waitcnt lgkmcnt(0)" ::: "memory");
    __builtin_amdgcn_s_barrier();
    {
      bf16x8 ka[4], va[4];
      const int g8s = (8 * w + 2 * q) ^ (2 * r15);
#pragma unroll
      for (int mi2 = 0; mi2 < 4; mi2++){
        int d = 16 * mi2 + r15;
        ka[mi2] = *(const bf16x8*)&sekv[d * 128 + g8s * 4];
      }
#pragma unroll
      for (int ni2 = 0; ni2 < 4; ni2++){
        int e = 16 * ni2 + r15;
        va[ni2] = *(const bf16x8*)&sekv[(64 + e) * 128 + g8s * 4];
      }
      __builtin_amdgcn_s_setprio(1);
#pragma unroll
      for (int mi2 = 0; mi2 < 4; mi2++)
#pragma unroll
        for (int ni2 = 0; ni2 < 4; ni2++)
          acc2[mi2][ni2] = __builtin_amdgcn_mfma_f32_16x16x32_bf16(
              ka[mi2], va[ni2], acc2[mi2][ni2], 0, 0, 0);
      __builtin_amdgcn_s_setprio(0);
    }
    __syncthreads();   // B2 (full): staged sx ready; sekv consumed
  }
#undef STAGE
  float* fb = (float*)smem;
#pragma unroll
  for (int mi2 = 0; mi2 < 4; mi2++)
#pragma unroll
    for (int ni2 = 0; ni2 < 4; ni2++)
#pragma unroll
      for (int r = 0; r < 4; r++){
        int d = 16 * mi2 + 4 * q + r, e = 16 * ni2 + r15;
        fb[w * 4096 + d * 64 + e] = acc2[mi2][ni2][r];
      }
  __syncthreads();
  {
    float* dst = pctx + ((size_t)((b * 8 + h) * 16 + cp)) * 4096 + tid * 16;
#pragma unroll
    for (int i = 0; i < 4; i++){
      int o = tid * 16 + 4 * i;
      float4 a = *(const float4*)(fb + o);
      float4 c = *(const float4*)(fb + 4096 + o);
      float4 d = *(const float4*)(fb + 8192 + o);
      float4 e = *(const float4*)(fb + 12288 + o);
      float4 s;
      s.x = a.x + c.x + d.x + e.x; s.y = a.y + c.y + d.y + e.y;
      s.z = a.z + c.z + d.z + e.z; s.w = a.w + c.w + d.w + e.w;
      *(float4*)(dst + 4 * i) = s;
    }
  }
  if (q == 0){
    float* rb = prs + ((size_t)((b * 8 + h) * 16 + cp)) * 128 + th * 64 + 32 * jh;
#pragma unroll
    for (int ni = 0; ni < 2; ni++) rb[16 * ni + r15] = rs[ni];
  }
}

// ---------------------------------------------------------------------------
// redmker v3 (R12-measured, unchanged): 16 chunk-pair partials, 256 blocks.
// ---------------------------------------------------------------------------
__global__ __launch_bounds__(256) void redmker(const float* __restrict__ pctx,
    const float* __restrict__ prs, const float* __restrict__ Wo,
    u16* __restrict__ mtf){
  __shared__ float ctxh8[8][68];
  __shared__ float woht[64][132];
  __shared__ float rsh[8];
  const int tid = threadIdx.x;
  const int bh = blockIdx.x, s = blockIdx.y;
  const int h = bh & 7;
  { // stage Wo^T slice for head h
    const int e4 = tid & 15, r0 = tid >> 4;
#pragma unroll
    for (int p = 0; p < 8; p++){
      int c = r0 + p * 16;
      float4 v = *(const float4*)(Wo + (size_t)c * 512 + h * 64 + 4 * e4);
      woht[4 * e4 + 0][c] = v.x; woht[4 * e4 + 1][c] = v.y;
      woht[4 * e4 + 2][c] = v.z; woht[4 * e4 + 3][c] = v.w;
    }
  }
  { // reduce 16 cp-partials of this 512-float slice (float2/thread)
    const float* base = pctx + (size_t)bh * 65536 + s * 512 + tid * 2;
    float2 a = {0.f, 0.f};
#pragma unroll 4
    for (int c = 0; c < 16; c++){
      float2 v = *(const float2*)(base + c * 4096);
      a.x += v.x; a.y += v.y;
    }
    const int i = tid * 2;
    ctxh8[i >> 6][i & 63] = a.x;
    ctxh8[(i + 1) >> 6][(i + 1) & 63] = a.y;
  }
  { // rowsum for the 8 d-rows of this slice (16 cps on lanes 0..15)
    const int dl = tid >> 5, c = tid & 31;
    const int dg = s * 8 + dl;
    float v = 0.f;
    if (c < 16){
      const float* rb = prs + (size_t)bh * 2048 + c * 128;
      v = rb[dg] + rb[64 + dg];
    }
    v += __shfl_xor(v, 1);  v += __shfl_xor(v, 2);
    v += __shfl_xor(v, 4);  v += __shfl_xor(v, 8);
    v += __shfl_xor(v, 16);
    if (c == 0) rsh[dl] = v;
  }
  __syncthreads();
  const int dl = tid >> 5, c0 = (tid & 31) * 4;
  const int d = s * 8 + dl;
  const float inv = 1.f / rsh[dl];
  float acc[4] = {0.f, 0.f, 0.f, 0.f};
  for (int e = 0; e < 64; e++){
    float cv = ctxh8[dl][e];
#pragma unroll
    for (int j = 0; j < 4; j++) acc[j] += cv * woht[e][c0 + j];
  }
  const int ks = d >> 5, lq = ((d >> 3) & 3) << 4, el = d & 7;
#pragma unroll
  for (int j = 0; j < 4; j++){
    int c = c0 + j;
    mtf[((size_t)(bh * 8 + (c >> 4)) * 2 + ks) * 512 + ((c & 15) | lq) * 8 + el]
        = f2bf(inv * acc[j]);
  }
}

// ---------------------------------------------------------------------------
// qout v9 (R11-measured) + T5 setprio + bq_ loads issued under stage drain.
// ---------------------------------------------------------------------------
__global__ __launch_bounds__(256, 3) void qout(const u16* __restrict__ xt,
    const u16* __restrict__ wqf, const float* __restrict__ bqs,
    const u16* __restrict__ mtf, const float* __restrict__ bo,
    float* __restrict__ out){
  __shared__ u16 smWq[8192];      // wqf(h): 16 KiB
  __shared__ u16 smWm[8192];      // mtf(h): 16 KiB
  __shared__ u16 smP[4][16 * 64]; // per-wave p[16t][64d]: 8 KiB
  const int tid = threadIdx.x;
  const int tt = blockIdx.x, b = blockIdx.y;
  const int w = tid >> 6, l = tid & 63, r15 = l & 15, q = l >> 4;
  const int t0 = tt * 64;
  const int m7 = 2 * (r15 & 7);
  const int t = t0 + w * 16 + r15;

  // x B-frags for this wave's 16 tokens (h-independent, pre-swizzled xt)
  bf16x8 xb[4];
#pragma unroll
  for (int ks = 0; ks < 4; ks++)
    xb[ks] = *(const bf16x8*)(xt + (size_t)(b * N_ + t) * 128 +
                              (((ks * 4 + q) ^ r15) * 8));

  u16* sp = smP[w];
  f32x4 acc3[8] = {};
  for (int h = 0; h < 8; h++){
    // stage wqf(h) [waves 0,1] + mtf(h) [waves 2,3]: 32 KiB linear copy
    {
      const char* gsrc = (w < 2)
          ? (const char*)(wqf + (size_t)h * 8192) + w * 8192 + l * 16
          : (const char*)(mtf + (size_t)(b * 8 + h) * 8192) + (w - 2) * 8192 + l * 16;
      char* ldst = (w < 2) ? (char*)smWq + w * 8192
                           : (char*)smWm + (w - 2) * 8192;
#pragma unroll
      for (int p = 0; p < 8; p++)
        __builtin_amdgcn_global_load_lds(
            (const __attribute__((address_space(1))) void*)(gsrc + p * 1024),
            (__attribute__((address_space(3))) void*)(ldst + p * 1024), 16, 0, 0);
    }
    // bq_ loads issue under the stage latency (independent of LDS)
    float bq_[4][4];
#pragma unroll
    for (int mi = 0; mi < 4; mi++){
      float4 v = *(const float4*)(bqs + h * 64 + 16 * mi + 4 * q);
      bq_[mi][0] = v.x; bq_[mi][1] = v.y; bq_[mi][2] = v.z; bq_[mi][3] = v.w;
    }
    __syncthreads();   // vmcnt drained: weight slabs ready

    // MFMA1: D[d 64][t 16], K=128; A = wq frags (LDS), B = xb (regs)
    f32x4 acc1[4] = {};
#pragma unroll
    for (int ks = 0; ks < 4; ks++){
      bf16x8 wqv[4];
#pragma unroll
      for (int mi = 0; mi < 4; mi++)
        wqv[mi] = *(const bf16x8*)&smWq[(mi * 4 + ks) * 512 + l * 8];
      __builtin_amdgcn_s_setprio(1);
#pragma unroll
      for (int mi = 0; mi < 4; mi++)
        acc1[mi] = __builtin_amdgcn_mfma_f32_16x16x32_bf16(
            wqv[mi], xb[ks], acc1[mi], 0, 0, 0);
      __builtin_amdgcn_s_setprio(0);
    }
    // exp + in-wave colsum + normalized p store (wave-private)
    {
      float ps = 0.f;
#pragma unroll
      for (int mi = 0; mi < 4; mi++)
#pragma unroll
        for (int r = 0; r < 4; r++){
          float e = __expf(acc1[mi][r] + bq_[mi][r]);
          acc1[mi][r] = e; ps += e;
        }
      ps += __shfl_xor(ps, 16); ps += __shfl_xor(ps, 32);
      const float ci = 1.f / ps;
#pragma unroll
      for (int mi = 0; mi < 4; mi++){
        uint2 pk;
        pk.x = cvtpk(acc1[mi][0] * ci, acc1[mi][1] * ci);
        pk.y = cvtpk(acc1[mi][2] * ci, acc1[mi][3] * ci);
        int g8s = (4 * mi + q) ^ m7;
        *(uint2*)&sp[r15 * 64 + g8s * 4] = pk;
      }
    }
    // MFMA2: out[c 128][t 16] += M_h . p, K=64; mf frags from LDS
#pragma unroll
    for (int ks2 = 0; ks2 < 2; ks2++){
      const int g8s = (8 * ks2 + 2 * q) ^ m7;
      bf16x8 pb = *(const bf16x8*)&sp[r15 * 64 + g8s * 4];
      bf16x8 mf[8];
#pragma unroll
      for (int mm = 0; mm < 8; mm++)
        mf[mm] = *(const bf16x8*)&smWm[(mm * 2 + ks2) * 512 + l * 8];
      __builtin_amdgcn_s_setprio(1);
#pragma unroll
      for (int mm = 0; mm < 8; mm++)
        acc3[mm] = __builtin_amdgcn_mfma_f32_16x16x32_bf16(
            mf[mm], pb, acc3[mm], 0, 0, 0);
      __builtin_amdgcn_s_setprio(0);
    }
    if (h < 7) __syncthreads();   // weights consumed -> safe to overwrite
  }
#pragma unroll
  for (int mi = 0; mi < 8; mi++){
    float4 bv = *(const float4*)(bo + 16 * mi + 4 * q);
    float bs[4] = {bv.x, bv.y, bv.z, bv.w};
#pragma unroll
    for (int r = 0; r < 4; r++){
      int c = 16 * mi + 4 * q + r;
      out[(size_t)(b * 128 + c) * N_ + t] = acc3[mi][r] + bs[r];
    }
  }
}

// ---------------------------------------------------------------------------
extern "C" void kernel_launch(void* const* d_in, const int* in_sizes, int n_in,
                              void* d_out, int out_size, void* d_ws, size_t ws_size,
                              hipStream_t stream){
  const float* x  = (const float*)d_in[0];
  const float* Wq = (const float*)d_in[1];
  const float* bq = (const float*)d_in[2];
  const float* Wk = (const float*)d_in[3];
  const float* bk = (const float*)d_in[4];
  const float* Wv = (const float*)d_in[5];
  const float* bv = (const float*)d_in[6];
  const float* Wo = (const float*)d_in[7];
  const float* bo = (const float*)d_in[8];
  float* out = (float*)d_out;

  char* ws = (char*)d_ws;
  u16*   xt     = (u16*)ws;                         // 16 MiB (pre-swizzled)
  u16*   wkvf   = (u16*)(ws + 16777216);            // 256 KiB
  u16*   wqf    = (u16*)(ws + 17039360);            // 128 KiB
  u16*   mtf    = (u16*)(ws + 17170432);            // 512 KiB
  float* bkv    = (float*)(ws + 17694720);          // 4 KiB
  float* bqs    = (float*)(ws + 17698816);          // 2 KiB
  float* pctx   = (float*)(ws + 18233344);          // 8 MiB (16 cp-partials)
  float* prs    = (float*)(ws + 35010560);          // 256 KiB

  pconvx <<<608, 256, 0, stream>>>(x, xt, Wq, bq, Wk, bk, Wv, bv,
                                   wkvf, wqf, bkv, bqs);
  kvctx  <<<dim3(16, 8, 4), 256, 0, stream>>>(xt, wkvf, bkv, pctx, prs);
  redmker<<<dim3(32, 8), 256, 0, stream>>>(pctx, prs, Wo, mtf);
  qout   <<<dim3(256, 4), 256, 0, stream>>>(xt, wqf, bqs, mtf, bo, out);
}